// Round 24
// baseline (194.519 us; speedup 1.0000x reference)
//
#include <hip/hip_runtime.h>

// GCN encoder: h1 = relu(x@fcW+fcb); h2 = relu(gcn(h1,W1,b1)); out = relu(gcn(h2,W2,b2))
// gcn(x,W,b)[i] = sum_{e:dst=i} (x@W)[src_e]*norm_e + (x@W)[i]*dinv[i]^2 + b
// Aggregation: dst-sorted CSR on device; per-node float4 gather, 8-way
// edge unroll with 4/2/1 remainder cascade (r24; r23's 4-way gave -3.5us,
// confirming the loop is MLP-limited, not BW-limited).
// GEMM: split-bf16 MFMA, pre-split zero-K-padded planes, 64x64 tile, BK=64,
// register prefetch (r17) + XCD-bijective 1-D grid swizzle (r20: -15us).
// FRONT-END: merged atomics+split+transpose kernel (r19); TWO-kernel scan
// (r21's merged scan regressed; reverted). No cooperative grid.sync
// (r18: ~60us per sync). No min-waves in __launch_bounds__ (r5/6: spills).

typedef unsigned short us;

namespace {
constexpr int NN = 20000;
constexpr int NE = 320000;
constexpr int IN_FT = 256, HID1 = 400, HID2 = 200, OUT_FT = 128;
constexpr int K1P = 448;  // HID1 padded to 64
constexpr int K2P = 256;  // HID2 padded to 64
constexpr int SBLK = 80;     // scan chunks
constexpr int SCHUNK = 250;  // elements per scan chunk (80*250 = 20000)
constexpr int NXS = NN * IN_FT / 8;                           // 640000
constexpr int NW = HID1 * IN_FT + HID2 * K1P + OUT_FT * K2P;  // 224768
using short8v = __attribute__((ext_vector_type(8))) short;
using f32x4 = __attribute__((ext_vector_type(4))) float;
}

__device__ __forceinline__ us f2bf(float f) {
  unsigned int u = __float_as_uint(f);
  u += 0x7FFFu + ((u >> 16) & 1u);  // round-to-nearest-even
  return (us)(u >> 16);
}
__device__ __forceinline__ float bf2f(us h) {
  return __uint_as_float(((unsigned int)h) << 16);
}

// fast zero of n float4-aligned words
__global__ __launch_bounds__(256) void zero_kernel(float4* __restrict__ p, int n4) {
  int i = blockIdx.x * 256 + threadIdx.x;
  if (i < n4) p[i] = make_float4(0.f, 0.f, 0.f, 0.f);
}

// deg/count atomics + x-split + weight transpose in ONE kernel (independent)
__global__ __launch_bounds__(256) void front_kernel(
    const int* __restrict__ dst, const float* __restrict__ ew,
    float* __restrict__ deg, int* __restrict__ cnt,
    const float* __restrict__ x, us* __restrict__ xh, us* __restrict__ xl,
    const float* __restrict__ fcW, const float* __restrict__ W1,
    const float* __restrict__ W2,
    us* __restrict__ fcWTh, us* __restrict__ fcWTl,
    us* __restrict__ W1Th, us* __restrict__ W1Tl,
    us* __restrict__ W2Th, us* __restrict__ W2Tl) {
  const int gid = blockIdx.x * 256 + threadIdx.x;
  const int gsz = gridDim.x * 256;
  for (int t = gid; t < NE + NN; t += gsz) {
    if (t < NE) {
      int d = dst[t];
      unsafeAtomicAdd(&deg[d], ew[t]);
      atomicAdd(&cnt[d], 1);
    } else {
      unsafeAtomicAdd(&deg[t - NE], 1.0f);  // self-loop weight 1
    }
  }
  for (int i = gid; i < NXS; i += gsz) {  // x -> bf16 hi/lo planes
    const float4 v0 = reinterpret_cast<const float4*>(x)[i * 2];
    const float4 v1 = reinterpret_cast<const float4*>(x)[i * 2 + 1];
    const float v[8] = {v0.x, v0.y, v0.z, v0.w, v1.x, v1.y, v1.z, v1.w};
    short8v h, l;
#pragma unroll
    for (int j = 0; j < 8; ++j) {
      us hh = f2bf(v[j]);
      h[j] = (short)hh;
      l[j] = (short)f2bf(v[j] - bf2f(hh));
    }
    reinterpret_cast<short8v*>(xh)[i] = h;
    reinterpret_cast<short8v*>(xl)[i] = l;
  }
  for (int widx = gid; widx < NW; widx += gsz) {  // W[K,N] -> [N][Kpad] hi/lo
    constexpr int N0 = HID1 * IN_FT;
    constexpr int N1 = HID2 * K1P;
    float v;
    us *th, *tl;
    int o;
    if (widx < N0) {
      o = widx;
      int n = o / IN_FT, k = o - n * IN_FT;  // Kpad == K == 256
      v = fcW[(size_t)k * HID1 + n];
      th = fcWTh; tl = fcWTl;
    } else if (widx < N0 + N1) {
      o = widx - N0;
      int n = o / K1P, k = o - n * K1P;
      v = (k < HID1) ? W1[(size_t)k * HID2 + n] : 0.f;
      th = W1Th; tl = W1Tl;
    } else {
      o = widx - N0 - N1;
      int n = o / K2P, k = o - n * K2P;
      v = (k < HID2) ? W2[(size_t)k * OUT_FT + n] : 0.f;
      th = W2Th; tl = W2Tl;
    }
    us h = f2bf(v);
    th[o] = h;
    tl[o] = f2bf(v - bf2f(h));
  }
}

// scan phase B: per-block count sums (tree reduce) + dinv elementwise
__global__ __launch_bounds__(256) void blocksum_dinv_kernel(const int* __restrict__ count,
                                                            int* __restrict__ bsum,
                                                            float* __restrict__ deg) {
  __shared__ int sdata[256];
  const int b = blockIdx.x, t = threadIdx.x;
  const int base = b * SCHUNK;
  int v = 0;
  if (t < SCHUNK) {
    const int i = base + t;
    v = count[i];
    float d = deg[i];
    deg[i] = d > 0.f ? rsqrtf(d) : 0.f;  // in place: deg -> dinv
  }
  sdata[t] = v;
  __syncthreads();
#pragma unroll
  for (int off = 128; off > 0; off >>= 1) {
    if (t < off) sdata[t] += sdata[t + off];
    __syncthreads();
  }
  if (t == 0) bsum[b] = sdata[0];
}

// scan phase C+D fused: inline per-block prefix of bsum + local scan
__global__ __launch_bounds__(256) void rowptr_kernel(const int* __restrict__ bsum,
                                                     int* __restrict__ count,
                                                     int* __restrict__ rowptr) {
  __shared__ int sdata[256];
  const int b = blockIdx.x, t = threadIdx.x;
  int contrib = (t < b) ? bsum[t] : 0;
  sdata[t] = contrib;
  __syncthreads();
#pragma unroll
  for (int off = 128; off > 0; off >>= 1) {
    if (t < off) sdata[t] += sdata[t + off];
    __syncthreads();
  }
  const int bpre = sdata[0];
  __syncthreads();
  const int base = b * SCHUNK;
  const int v = (t < SCHUNK) ? count[base + t] : 0;
  sdata[t] = v;
  __syncthreads();
#pragma unroll
  for (int off = 1; off < 256; off <<= 1) {
    int u = 0;
    if (t >= off) u = sdata[t - off];
    __syncthreads();
    if (t >= off) sdata[t] += u;
    __syncthreads();
  }
  const int excl = sdata[t] - v + bpre;
  if (t < SCHUNK) {
    rowptr[base + t] = excl;
    count[base + t] = excl;  // scatter fill cursor
  }
  if (b == SBLK - 1 && t == 0) rowptr[NN] = NE;  // total is static
}

// scatter edges into dst-sorted order, computing norm inline
__global__ __launch_bounds__(256) void scatter_kernel(const int* __restrict__ src,
                                                      const int* __restrict__ dst,
                                                      const float* __restrict__ ew,
                                                      const float* __restrict__ dinv,
                                                      int* __restrict__ fill,
                                                      int* __restrict__ srcS,
                                                      float* __restrict__ wS) {
  int e = blockIdx.x * 256 + threadIdx.x;
  if (e >= NE) return;
  int s = src[e], d = dst[e];
  int pos = atomicAdd(&fill[d], 1);
  srcS[pos] = s;
  wS[pos] = dinv[s] * ew[e] * dinv[d];
}

// C[M,N] = A[M,KAP] @ BT[N,KAP]^T from pre-split zero-K-padded planes.
// 64x64 tile, BK=64, 4 waves (2x2), reg prefetch, XCD-bijective swizzle.
template <int KAP, bool BIAS, bool RELU, bool SPLIT>
__global__ __launch_bounds__(256) void gemm64_kernel(
    const us* __restrict__ Ah, const us* __restrict__ Al,
    const us* __restrict__ BTh, const us* __restrict__ BTl,
    const float* __restrict__ bias, float* __restrict__ Cf,
    us* __restrict__ Ch, us* __restrict__ Cl,
    int M, int N, int NPAD, int nBx) {
  constexpr int BK = 64;
  constexpr int LDK = BK + 4;  // frag reads spread 2-way max (free)
  __shared__ us Ash[64][LDK];
  __shared__ us Asl[64][LDK];
  __shared__ us Bsh[64][LDK];
  __shared__ us Bsl[64][LDK];
  // XCD-bijective swizzle (m204): physical blocks go to XCD (id % 8);
  // give XCD x the contiguous logical range so A panels stay in its L2.
  const int nwg = gridDim.x;
  const int q = nwg >> 3, r = nwg & 7;
  const int xcd = blockIdx.x & 7, bi = blockIdx.x >> 3;
  const int swz = (xcd < r ? xcd * (q + 1) : r * (q + 1) + (xcd - r) * q) + bi;
  const int by = swz / nBx, bx = swz - by * nBx;
  const int m0 = by * 64, n0 = bx * 64;

  const int tid = threadIdx.x;
  const int lane = tid & 63;
  const int wid = tid >> 6;
  const int wm = wid >> 1, wn = wid & 1;  // 2x2 wave grid
  const int sr = tid >> 2, sko = (tid & 3) * 16;  // staging: row, k-offset
  const int arow = m0 + sr;
  const int brow = n0 + sr;
  const int l15 = lane & 15, kg = lane >> 4;
  const short8v zv = {0, 0, 0, 0, 0, 0, 0, 0};

  f32x4 acc[2][2];
#pragma unroll
  for (int i = 0; i < 2; ++i)
#pragma unroll
    for (int j = 0; j < 2; ++j)
#pragma unroll
      for (int c = 0; c < 4; ++c) acc[i][j][c] = 0.f;

  short8v pa0h, pa1h, pa0l, pa1l, pb0h, pb1h, pb0l, pb1l;
  auto gload = [&](int k0) {
    pa0h = pa1h = pa0l = pa1l = zv;
    pb0h = pb1h = pb0l = pb1l = zv;
    if (arow < M) {
      const size_t off = (size_t)arow * KAP + k0 + sko;
      pa0h = *reinterpret_cast<const short8v*>(Ah + off);
      pa1h = *reinterpret_cast<const short8v*>(Ah + off + 8);
      pa0l = *reinterpret_cast<const short8v*>(Al + off);
      pa1l = *reinterpret_cast<const short8v*>(Al + off + 8);
    }
    if (brow < N) {
      const size_t off = (size_t)brow * KAP + k0 + sko;
      pb0h = *reinterpret_cast<const short8v*>(BTh + off);
      pb1h = *reinterpret_cast<const short8v*>(BTh + off + 8);
      pb0l = *reinterpret_cast<const short8v*>(BTl + off);
      pb1l = *reinterpret_cast<const short8v*>(BTl + off + 8);
    }
  };
  auto sstore = [&]() {
    *reinterpret_cast<short8v*>(&Ash[sr][sko]) = pa0h;
    *reinterpret_cast<short8v*>(&Ash[sr][sko + 8]) = pa1h;
    *reinterpret_cast<short8v*>(&Asl[sr][sko]) = pa0l;
    *reinterpret_cast<short8v*>(&Asl[sr][sko + 8]) = pa1l;
    *reinterpret_cast<short8v*>(&Bsh[sr][sko]) = pb0h;
    *reinterpret_cast<short8v*>(&Bsh[sr][sko + 8]) = pb1h;
    *reinterpret_cast<short8v*>(&Bsl[sr][sko]) = pb0l;
    *reinterpret_cast<short8v*>(&Bsl[sr][sko + 8]) = pb1l;
  };

  gload(0);
  sstore();
  __syncthreads();
#pragma unroll
  for (int k0 = 0; k0 < KAP; k0 += BK) {
    const bool more = (k0 + BK < KAP);
    if (more) gload(k0 + BK);  // in flight under this step's compute
#pragma unroll
    for (int kc = 0; kc < BK; kc += 32) {
      short8v afh[2], afl[2], bfh[2], bfl[2];
#pragma unroll
      for (int mf = 0; mf < 2; ++mf) {
        const int rr = wm * 32 + mf * 16 + l15;
        afh[mf] = *reinterpret_cast<const short8v*>(&Ash[rr][kc + kg * 8]);
        afl[mf] = *reinterpret_cast<const short8v*>(&Asl[rr][kc + kg * 8]);
      }
#pragma unroll
      for (int nf = 0; nf < 2; ++nf) {
        const int cc = wn * 32 + nf * 16 + l15;
        bfh[nf] = *reinterpret_cast<const short8v*>(&Bsh[cc][kc + kg * 8]);
        bfl[nf] = *reinterpret_cast<const short8v*>(&Bsl[cc][kc + kg * 8]);
      }
#pragma unroll
      for (int mf = 0; mf < 2; ++mf)
#pragma unroll
        for (int nf = 0; nf < 2; ++nf) {
          acc[mf][nf] = __builtin_amdgcn_mfma_f32_16x16x32_bf16(afh[mf], bfh[nf], acc[mf][nf], 0, 0, 0);
          acc[mf][nf] = __builtin_amdgcn_mfma_f32_16x16x32_bf16(afh[mf], bfl[nf], acc[mf][nf], 0, 0, 0);
          acc[mf][nf] = __builtin_amdgcn_mfma_f32_16x16x32_bf16(afl[mf], bfh[nf], acc[mf][nf], 0, 0, 0);
        }
    }
    __syncthreads();
    if (more) {
      sstore();
      __syncthreads();
    }
  }

  // epilogue: C/D layout col=lane&15, row=(lane>>4)*4+reg (guide §3, m89/m91)
#pragma unroll
  for (int nf = 0; nf < 2; ++nf) {
    const int col = n0 + wn * 32 + nf * 16 + l15;
    float bb = 0.f;
    if (BIAS && col < N) bb = bias[col];
#pragma unroll
    for (int mf = 0; mf < 2; ++mf) {
      const int rbase = m0 + wm * 32 + mf * 16 + kg * 4;
#pragma unroll
      for (int i = 0; i < 4; ++i) {
        const int row = rbase + i;
        if (row >= M) continue;
        if (col < N) {
          float v = acc[mf][nf][i];
          if (BIAS) v += bb;
          if (RELU) v = fmaxf(v, 0.f);
          if (SPLIT) {
            us h = f2bf(v);
            Ch[(size_t)row * NPAD + col] = h;
            Cl[(size_t)row * NPAD + col] = f2bf(v - bf2f(h));
          } else {
            Cf[(size_t)row * N + col] = v;
          }
        } else if (SPLIT && col < NPAD) {  // zero the K-pad for next GEMM
          Ch[(size_t)row * NPAD + col] = 0;
          Cl[(size_t)row * NPAD + col] = 0;
        }
      }
    }
  }
}

// Fused gather-aggregate + self-loop + bias + relu.
// NPW nodes/wave; F/4 lanes per node, ONE float4 per edge per lane.
// 8-way edge unroll with 4/2/1 remainder cascade: up to 8 independent
// load->FMA chains in flight per wave (MLP-limited loop, r23/r24).
// SPLIT: write bf16 hi/lo planes with row stride OST, zero-pad cols [F,OST).
template <int F, int OST, int NPW, bool SPLIT>
__global__ __launch_bounds__(256) void agg_gather_kernel(const int* __restrict__ rowptr,
                                                         const int* __restrict__ srcS,
                                                         const float* __restrict__ wS,
                                                         const float* __restrict__ t,
                                                         const float* __restrict__ dinv,
                                                         const float* __restrict__ bias,
                                                         float* __restrict__ out,
                                                         us* __restrict__ oh,
                                                         us* __restrict__ ol) {
  constexpr int LPN = F / 4;     // float4 lanes per node
  constexpr int LPNP = OST / 4;  // lanes incl. pad
  const int wv = threadIdx.x >> 6;
  const int lane = threadIdx.x & 63;
  const int sub = (NPW == 2) ? (lane >> 5) : 0;
  const int l = (NPW == 2) ? (lane & 31) : lane;
  const int node = blockIdx.x * (4 * NPW) + wv * NPW + sub;
  if (node >= NN) return;
  if (l >= LPN) {
    if (SPLIT && l < LPNP) {  // zero the K-pad for the next GEMM
      ushort4 z = make_ushort4(0, 0, 0, 0);
      *reinterpret_cast<ushort4*>(oh + (size_t)node * OST + l * 4) = z;
      *reinterpret_cast<ushort4*>(ol + (size_t)node * OST + l * 4) = z;
    }
    return;  // no barriers/shuffles below: safe exit
  }
  const int beg = rowptr[node], end = rowptr[node + 1];
  const size_t fo = (size_t)l * 4;
  float4 a[8];
#pragma unroll
  for (int c = 0; c < 8; ++c) a[c] = make_float4(0.f, 0.f, 0.f, 0.f);
  int j = beg;
  for (; j + 7 < end; j += 8) {  // 8 independent load->FMA chains
    int s[8];
    float w[8];
#pragma unroll
    for (int c = 0; c < 8; ++c) { s[c] = srcS[j + c]; w[c] = wS[j + c]; }
    float4 v[8];
#pragma unroll
    for (int c = 0; c < 8; ++c)
      v[c] = *reinterpret_cast<const float4*>(t + (size_t)s[c] * F + fo);
#pragma unroll
    for (int c = 0; c < 8; ++c) {
      a[c].x = fmaf(v[c].x, w[c], a[c].x);
      a[c].y = fmaf(v[c].y, w[c], a[c].y);
      a[c].z = fmaf(v[c].z, w[c], a[c].z);
      a[c].w = fmaf(v[c].w, w[c], a[c].w);
    }
  }
  if (j + 3 < end) {  // 4-edge remainder, still parallel chains
    int s[4];
    float w[4];
#pragma unroll
    for (int c = 0; c < 4; ++c) { s[c] = srcS[j + c]; w[c] = wS[j + c]; }
    float4 v[4];
#pragma unroll
    for (int c = 0; c < 4; ++c)
      v[c] = *reinterpret_cast<const float4*>(t + (size_t)s[c] * F + fo);
#pragma unroll
    for (int c = 0; c < 4; ++c) {
      a[c].x = fmaf(v[c].x, w[c], a[c].x);
      a[c].y = fmaf(v[c].y, w[c], a[c].y);
      a[c].z = fmaf(v[c].z, w[c], a[c].z);
      a[c].w = fmaf(v[c].w, w[c], a[c].w);
    }
    j += 4;
  }
  if (j + 1 < end) {  // 2-edge remainder
    const int s0 = srcS[j], s1 = srcS[j + 1];
    const float w0 = wS[j], w1 = wS[j + 1];
    const float4 v0 = *reinterpret_cast<const float4*>(t + (size_t)s0 * F + fo);
    const float4 v1 = *reinterpret_cast<const float4*>(t + (size_t)s1 * F + fo);
    a[0].x = fmaf(v0.x, w0, a[0].x); a[0].y = fmaf(v0.y, w0, a[0].y);
    a[0].z = fmaf(v0.z, w0, a[0].z); a[0].w = fmaf(v0.w, w0, a[0].w);
    a[1].x = fmaf(v1.x, w1, a[1].x); a[1].y = fmaf(v1.y, w1, a[1].y);
    a[1].z = fmaf(v1.z, w1, a[1].z); a[1].w = fmaf(v1.w, w1, a[1].w);
    j += 2;
  }
  if (j < end) {  // 1-edge remainder
    const int s0 = srcS[j];
    const float w0 = wS[j];
    const float4 v0 = *reinterpret_cast<const float4*>(t + (size_t)s0 * F + fo);
    a[0].x = fmaf(v0.x, w0, a[0].x); a[0].y = fmaf(v0.y, w0, a[0].y);
    a[0].z = fmaf(v0.z, w0, a[0].z); a[0].w = fmaf(v0.w, w0, a[0].w);
  }
  const float di = dinv[node];
  const float sw = di * di;
  const float4 tv = *reinterpret_cast<const float4*>(t + (size_t)node * F + fo);
  const float4 bb = *reinterpret_cast<const float4*>(bias + fo);
  const float sx = ((a[0].x + a[1].x) + (a[2].x + a[3].x)) + ((a[4].x + a[5].x) + (a[6].x + a[7].x));
  const float sy = ((a[0].y + a[1].y) + (a[2].y + a[3].y)) + ((a[4].y + a[5].y) + (a[6].y + a[7].y));
  const float sz = ((a[0].z + a[1].z) + (a[2].z + a[3].z)) + ((a[4].z + a[5].z) + (a[6].z + a[7].z));
  const float sw4 = ((a[0].w + a[1].w) + (a[2].w + a[3].w)) + ((a[4].w + a[5].w) + (a[6].w + a[7].w));
  float4 o;
  o.x = fmaxf(fmaf(tv.x, sw, sx) + bb.x, 0.f);
  o.y = fmaxf(fmaf(tv.y, sw, sy) + bb.y, 0.f);
  o.z = fmaxf(fmaf(tv.z, sw, sz) + bb.z, 0.f);
  o.w = fmaxf(fmaf(tv.w, sw, sw4) + bb.w, 0.f);
  if (SPLIT) {
    ushort4 hv, lv;
    hv.x = f2bf(o.x); lv.x = f2bf(o.x - bf2f(hv.x));
    hv.y = f2bf(o.y); lv.y = f2bf(o.y - bf2f(hv.y));
    hv.z = f2bf(o.z); lv.z = f2bf(o.z - bf2f(hv.z));
    hv.w = f2bf(o.w); lv.w = f2bf(o.w - bf2f(hv.w));
    *reinterpret_cast<ushort4*>(oh + (size_t)node * OST + fo) = hv;
    *reinterpret_cast<ushort4*>(ol + (size_t)node * OST + fo) = lv;
  } else {
    *reinterpret_cast<float4*>(out + (size_t)node * F + fo) = o;
  }
}

extern "C" void kernel_launch(void* const* d_in, const int* in_sizes, int n_in,
                              void* d_out, int out_size, void* d_ws, size_t ws_size,
                              hipStream_t stream) {
  const float* x = (const float*)d_in[0];
  const int* ei = (const int*)d_in[1];  // int32 per harness conversion
  const float* ea = (const float*)d_in[2];
  const float* fcW = (const float*)d_in[3];
  const float* fcb = (const float*)d_in[4];
  const float* W1 = (const float*)d_in[5];
  const float* b1 = (const float*)d_in[6];
  const float* W2 = (const float*)d_in[7];
  const float* b2 = (const float*)d_in[8];
  const int* srcIdx = ei;       // edge_index[0]
  const int* dstIdx = ei + NE;  // edge_index[1]

  char* ws = (char*)d_ws;
  constexpr size_t KB_ = 1u << 10;
  float* dinv = (float*)(ws);                    // 80000 B (doubles as deg)
  int* cnt = (int*)(ws + 80000);                 // 80000 B (count -> cursor)
  int* rowptr = (int*)(ws + 160000);             // 80004 B
  int* bsum = (int*)(ws + 244 * KB_);            // 320 B
  int* srcS = (int*)(ws + 256 * KB_);            // 1.28 MB
  float* wS = (float*)(ws + 1536 * KB_);         // 1.28 MB
  us* fcWTh = (us*)(ws + 2880 * KB_);            // 204800 B
  us* fcWTl = (us*)(ws + 3088 * KB_);
  us* W1Th = (us*)(ws + 3296 * KB_);             // 200x448x2 = 179200 B
  us* W1Tl = (us*)(ws + 3472 * KB_);
  us* W2Th = (us*)(ws + 3648 * KB_);             // 128x256x2 = 65536 B
  us* W2Tl = (us*)(ws + 3712 * KB_);             // ends exactly at 3776 KB
  us* xh = (us*)(ws + 3776 * KB_);               // 10.24 MB
  us* xl = (us*)(ws + 13784 * KB_);              // ends ~23.8 MB
  us* h1h = (us*)(ws + 23800 * KB_);             // 20000x448x2 = 17.92 MB
  us* h1l = (us*)(ws + 41350 * KB_);             // ends ~57.5 MB (peak)
  float* t1 = (float*)(ws + 3776 * KB_);         // 16 MB (x dead); also t2
  us* h2h = (us*)(ws + 23800 * KB_);             // 10.24 MB (h1 dead)
  us* h2l = (us*)(ws + 33800 * KB_);
  float* t2 = (float*)(ws + 3776 * KB_);         // 10.24 MB (t1 dead)

  // --- front-end: zero; {atomics + x-split + w-transpose}; scan; scatter ---
  zero_kernel<<<(40000 / 4 + 255) / 256, 256, 0, stream>>>((float4*)ws, 40000 / 4);
  front_kernel<<<2560, 256, 0, stream>>>(dstIdx, ea, dinv, cnt, x, xh, xl,
                                         fcW, W1, W2, fcWTh, fcWTl,
                                         W1Th, W1Tl, W2Th, W2Tl);
  blocksum_dinv_kernel<<<SBLK, 256, 0, stream>>>(cnt, bsum, dinv);
  rowptr_kernel<<<SBLK, 256, 0, stream>>>(bsum, cnt, rowptr);
  scatter_kernel<<<(NE + 255) / 256, 256, 0, stream>>>(srcIdx, dstIdx, ea, dinv, cnt, srcS, wS);

  const int MBLK = (NN + 63) / 64;  // 313 row blocks

  // --- h1 = relu(x @ fcW + fcb), bf16 hi/lo planes [NN][448] ---
  gemm64_kernel<IN_FT, true, true, true><<<7 * MBLK, 256, 0, stream>>>(
      xh, xl, fcWTh, fcWTl, fcb, nullptr, h1h, h1l, NN, HID1, K1P, 7);

  // --- layer 1: t1 = h1 @ W1 (fp32); h2 = relu(agg(t1)+..) planes [NN][256] ---
  gemm64_kernel<K1P, false, false, false><<<4 * MBLK, 256, 0, stream>>>(
      h1h, h1l, W1Th, W1Tl, nullptr, t1, nullptr, nullptr, NN, HID2, HID2, 4);
  agg_gather_kernel<HID2, K2P, 1, true><<<(NN + 3) / 4, 256, 0, stream>>>(
      rowptr, srcS, wS, t1, dinv, b1, nullptr, h2h, h2l);

  // --- layer 2: t2 = h2 @ W2 (fp32); out = relu(agg(t2)+..) fp32 ---
  gemm64_kernel<K2P, false, false, false><<<2 * MBLK, 256, 0, stream>>>(
      h2h, h2l, W2Th, W2Tl, nullptr, t2, nullptr, nullptr, NN, OUT_FT, OUT_FT, 2);
  agg_gather_kernel<OUT_FT, OUT_FT, 2, false><<<(NN + 7) / 8, 256, 0, stream>>>(
      rowptr, srcS, wS, t2, dinv, b2, (float*)d_out, nullptr, nullptr);
}

// Round 25
// 190.152 us; speedup vs baseline: 1.0230x; 1.0230x over previous
//
#include <hip/hip_runtime.h>

// GCN encoder: h1 = relu(x@fcW+fcb); h2 = relu(gcn(h1,W1,b1)); out = relu(gcn(h2,W2,b2))
// gcn(x,W,b)[i] = sum_{e:dst=i} (x@W)[src_e]*norm_e + (x@W)[i]*dinv[i]^2 + b
// Aggregation: dst-sorted CSR on device; per-node float4 gather, 4-way
// edge unroll (r23 champion; r24's 8-way regressed -- mean degree ~16 means
// the 8-wide loop runs <=1x/node and the remainder cascade adds overhead).
// GEMM: split-bf16 MFMA, pre-split zero-K-padded planes, 64x64 tile, BK=64,
// register prefetch (r17) + XCD-bijective 1-D grid swizzle (r20: -15us).
// FRONT-END: merged atomics+split+transpose kernel (r19); TWO-kernel scan
// (r21's merged scan regressed; reverted). No cooperative grid.sync
// (r18: ~60us per sync). No min-waves in __launch_bounds__ (r5/6: spills).
// ROUND-23 CHAMPION (190.3 us), restored after r24's 8-way experiment.

typedef unsigned short us;

namespace {
constexpr int NN = 20000;
constexpr int NE = 320000;
constexpr int IN_FT = 256, HID1 = 400, HID2 = 200, OUT_FT = 128;
constexpr int K1P = 448;  // HID1 padded to 64
constexpr int K2P = 256;  // HID2 padded to 64
constexpr int SBLK = 80;     // scan chunks
constexpr int SCHUNK = 250;  // elements per scan chunk (80*250 = 20000)
constexpr int NXS = NN * IN_FT / 8;                           // 640000
constexpr int NW = HID1 * IN_FT + HID2 * K1P + OUT_FT * K2P;  // 224768
using short8v = __attribute__((ext_vector_type(8))) short;
using f32x4 = __attribute__((ext_vector_type(4))) float;
}

__device__ __forceinline__ us f2bf(float f) {
  unsigned int u = __float_as_uint(f);
  u += 0x7FFFu + ((u >> 16) & 1u);  // round-to-nearest-even
  return (us)(u >> 16);
}
__device__ __forceinline__ float bf2f(us h) {
  return __uint_as_float(((unsigned int)h) << 16);
}

// fast zero of n float4-aligned words
__global__ __launch_bounds__(256) void zero_kernel(float4* __restrict__ p, int n4) {
  int i = blockIdx.x * 256 + threadIdx.x;
  if (i < n4) p[i] = make_float4(0.f, 0.f, 0.f, 0.f);
}

// deg/count atomics + x-split + weight transpose in ONE kernel (independent)
__global__ __launch_bounds__(256) void front_kernel(
    const int* __restrict__ dst, const float* __restrict__ ew,
    float* __restrict__ deg, int* __restrict__ cnt,
    const float* __restrict__ x, us* __restrict__ xh, us* __restrict__ xl,
    const float* __restrict__ fcW, const float* __restrict__ W1,
    const float* __restrict__ W2,
    us* __restrict__ fcWTh, us* __restrict__ fcWTl,
    us* __restrict__ W1Th, us* __restrict__ W1Tl,
    us* __restrict__ W2Th, us* __restrict__ W2Tl) {
  const int gid = blockIdx.x * 256 + threadIdx.x;
  const int gsz = gridDim.x * 256;
  for (int t = gid; t < NE + NN; t += gsz) {
    if (t < NE) {
      int d = dst[t];
      unsafeAtomicAdd(&deg[d], ew[t]);
      atomicAdd(&cnt[d], 1);
    } else {
      unsafeAtomicAdd(&deg[t - NE], 1.0f);  // self-loop weight 1
    }
  }
  for (int i = gid; i < NXS; i += gsz) {  // x -> bf16 hi/lo planes
    const float4 v0 = reinterpret_cast<const float4*>(x)[i * 2];
    const float4 v1 = reinterpret_cast<const float4*>(x)[i * 2 + 1];
    const float v[8] = {v0.x, v0.y, v0.z, v0.w, v1.x, v1.y, v1.z, v1.w};
    short8v h, l;
#pragma unroll
    for (int j = 0; j < 8; ++j) {
      us hh = f2bf(v[j]);
      h[j] = (short)hh;
      l[j] = (short)f2bf(v[j] - bf2f(hh));
    }
    reinterpret_cast<short8v*>(xh)[i] = h;
    reinterpret_cast<short8v*>(xl)[i] = l;
  }
  for (int widx = gid; widx < NW; widx += gsz) {  // W[K,N] -> [N][Kpad] hi/lo
    constexpr int N0 = HID1 * IN_FT;
    constexpr int N1 = HID2 * K1P;
    float v;
    us *th, *tl;
    int o;
    if (widx < N0) {
      o = widx;
      int n = o / IN_FT, k = o - n * IN_FT;  // Kpad == K == 256
      v = fcW[(size_t)k * HID1 + n];
      th = fcWTh; tl = fcWTl;
    } else if (widx < N0 + N1) {
      o = widx - N0;
      int n = o / K1P, k = o - n * K1P;
      v = (k < HID1) ? W1[(size_t)k * HID2 + n] : 0.f;
      th = W1Th; tl = W1Tl;
    } else {
      o = widx - N0 - N1;
      int n = o / K2P, k = o - n * K2P;
      v = (k < HID2) ? W2[(size_t)k * OUT_FT + n] : 0.f;
      th = W2Th; tl = W2Tl;
    }
    us h = f2bf(v);
    th[o] = h;
    tl[o] = f2bf(v - bf2f(h));
  }
}

// scan phase B: per-block count sums (tree reduce) + dinv elementwise
__global__ __launch_bounds__(256) void blocksum_dinv_kernel(const int* __restrict__ count,
                                                            int* __restrict__ bsum,
                                                            float* __restrict__ deg) {
  __shared__ int sdata[256];
  const int b = blockIdx.x, t = threadIdx.x;
  const int base = b * SCHUNK;
  int v = 0;
  if (t < SCHUNK) {
    const int i = base + t;
    v = count[i];
    float d = deg[i];
    deg[i] = d > 0.f ? rsqrtf(d) : 0.f;  // in place: deg -> dinv
  }
  sdata[t] = v;
  __syncthreads();
#pragma unroll
  for (int off = 128; off > 0; off >>= 1) {
    if (t < off) sdata[t] += sdata[t + off];
    __syncthreads();
  }
  if (t == 0) bsum[b] = sdata[0];
}

// scan phase C+D fused: inline per-block prefix of bsum + local scan
__global__ __launch_bounds__(256) void rowptr_kernel(const int* __restrict__ bsum,
                                                     int* __restrict__ count,
                                                     int* __restrict__ rowptr) {
  __shared__ int sdata[256];
  const int b = blockIdx.x, t = threadIdx.x;
  int contrib = (t < b) ? bsum[t] : 0;
  sdata[t] = contrib;
  __syncthreads();
#pragma unroll
  for (int off = 128; off > 0; off >>= 1) {
    if (t < off) sdata[t] += sdata[t + off];
    __syncthreads();
  }
  const int bpre = sdata[0];
  __syncthreads();
  const int base = b * SCHUNK;
  const int v = (t < SCHUNK) ? count[base + t] : 0;
  sdata[t] = v;
  __syncthreads();
#pragma unroll
  for (int off = 1; off < 256; off <<= 1) {
    int u = 0;
    if (t >= off) u = sdata[t - off];
    __syncthreads();
    if (t >= off) sdata[t] += u;
    __syncthreads();
  }
  const int excl = sdata[t] - v + bpre;
  if (t < SCHUNK) {
    rowptr[base + t] = excl;
    count[base + t] = excl;  // scatter fill cursor
  }
  if (b == SBLK - 1 && t == 0) rowptr[NN] = NE;  // total is static
}

// scatter edges into dst-sorted order, computing norm inline
__global__ __launch_bounds__(256) void scatter_kernel(const int* __restrict__ src,
                                                      const int* __restrict__ dst,
                                                      const float* __restrict__ ew,
                                                      const float* __restrict__ dinv,
                                                      int* __restrict__ fill,
                                                      int* __restrict__ srcS,
                                                      float* __restrict__ wS) {
  int e = blockIdx.x * 256 + threadIdx.x;
  if (e >= NE) return;
  int s = src[e], d = dst[e];
  int pos = atomicAdd(&fill[d], 1);
  srcS[pos] = s;
  wS[pos] = dinv[s] * ew[e] * dinv[d];
}

// C[M,N] = A[M,KAP] @ BT[N,KAP]^T from pre-split zero-K-padded planes.
// 64x64 tile, BK=64, 4 waves (2x2), reg prefetch, XCD-bijective swizzle.
template <int KAP, bool BIAS, bool RELU, bool SPLIT>
__global__ __launch_bounds__(256) void gemm64_kernel(
    const us* __restrict__ Ah, const us* __restrict__ Al,
    const us* __restrict__ BTh, const us* __restrict__ BTl,
    const float* __restrict__ bias, float* __restrict__ Cf,
    us* __restrict__ Ch, us* __restrict__ Cl,
    int M, int N, int NPAD, int nBx) {
  constexpr int BK = 64;
  constexpr int LDK = BK + 4;  // frag reads spread 2-way max (free)
  __shared__ us Ash[64][LDK];
  __shared__ us Asl[64][LDK];
  __shared__ us Bsh[64][LDK];
  __shared__ us Bsl[64][LDK];
  // XCD-bijective swizzle (m204): physical blocks go to XCD (id % 8);
  // give XCD x the contiguous logical range so A panels stay in its L2.
  const int nwg = gridDim.x;
  const int q = nwg >> 3, r = nwg & 7;
  const int xcd = blockIdx.x & 7, bi = blockIdx.x >> 3;
  const int swz = (xcd < r ? xcd * (q + 1) : r * (q + 1) + (xcd - r) * q) + bi;
  const int by = swz / nBx, bx = swz - by * nBx;
  const int m0 = by * 64, n0 = bx * 64;

  const int tid = threadIdx.x;
  const int lane = tid & 63;
  const int wid = tid >> 6;
  const int wm = wid >> 1, wn = wid & 1;  // 2x2 wave grid
  const int sr = tid >> 2, sko = (tid & 3) * 16;  // staging: row, k-offset
  const int arow = m0 + sr;
  const int brow = n0 + sr;
  const int l15 = lane & 15, kg = lane >> 4;
  const short8v zv = {0, 0, 0, 0, 0, 0, 0, 0};

  f32x4 acc[2][2];
#pragma unroll
  for (int i = 0; i < 2; ++i)
#pragma unroll
    for (int j = 0; j < 2; ++j)
#pragma unroll
      for (int c = 0; c < 4; ++c) acc[i][j][c] = 0.f;

  short8v pa0h, pa1h, pa0l, pa1l, pb0h, pb1h, pb0l, pb1l;
  auto gload = [&](int k0) {
    pa0h = pa1h = pa0l = pa1l = zv;
    pb0h = pb1h = pb0l = pb1l = zv;
    if (arow < M) {
      const size_t off = (size_t)arow * KAP + k0 + sko;
      pa0h = *reinterpret_cast<const short8v*>(Ah + off);
      pa1h = *reinterpret_cast<const short8v*>(Ah + off + 8);
      pa0l = *reinterpret_cast<const short8v*>(Al + off);
      pa1l = *reinterpret_cast<const short8v*>(Al + off + 8);
    }
    if (brow < N) {
      const size_t off = (size_t)brow * KAP + k0 + sko;
      pb0h = *reinterpret_cast<const short8v*>(BTh + off);
      pb1h = *reinterpret_cast<const short8v*>(BTh + off + 8);
      pb0l = *reinterpret_cast<const short8v*>(BTl + off);
      pb1l = *reinterpret_cast<const short8v*>(BTl + off + 8);
    }
  };
  auto sstore = [&]() {
    *reinterpret_cast<short8v*>(&Ash[sr][sko]) = pa0h;
    *reinterpret_cast<short8v*>(&Ash[sr][sko + 8]) = pa1h;
    *reinterpret_cast<short8v*>(&Asl[sr][sko]) = pa0l;
    *reinterpret_cast<short8v*>(&Asl[sr][sko + 8]) = pa1l;
    *reinterpret_cast<short8v*>(&Bsh[sr][sko]) = pb0h;
    *reinterpret_cast<short8v*>(&Bsh[sr][sko + 8]) = pb1h;
    *reinterpret_cast<short8v*>(&Bsl[sr][sko]) = pb0l;
    *reinterpret_cast<short8v*>(&Bsl[sr][sko + 8]) = pb1l;
  };

  gload(0);
  sstore();
  __syncthreads();
#pragma unroll
  for (int k0 = 0; k0 < KAP; k0 += BK) {
    const bool more = (k0 + BK < KAP);
    if (more) gload(k0 + BK);  // in flight under this step's compute
#pragma unroll
    for (int kc = 0; kc < BK; kc += 32) {
      short8v afh[2], afl[2], bfh[2], bfl[2];
#pragma unroll
      for (int mf = 0; mf < 2; ++mf) {
        const int rr = wm * 32 + mf * 16 + l15;
        afh[mf] = *reinterpret_cast<const short8v*>(&Ash[rr][kc + kg * 8]);
        afl[mf] = *reinterpret_cast<const short8v*>(&Asl[rr][kc + kg * 8]);
      }
#pragma unroll
      for (int nf = 0; nf < 2; ++nf) {
        const int cc = wn * 32 + nf * 16 + l15;
        bfh[nf] = *reinterpret_cast<const short8v*>(&Bsh[cc][kc + kg * 8]);
        bfl[nf] = *reinterpret_cast<const short8v*>(&Bsl[cc][kc + kg * 8]);
      }
#pragma unroll
      for (int mf = 0; mf < 2; ++mf)
#pragma unroll
        for (int nf = 0; nf < 2; ++nf) {
          acc[mf][nf] = __builtin_amdgcn_mfma_f32_16x16x32_bf16(afh[mf], bfh[nf], acc[mf][nf], 0, 0, 0);
          acc[mf][nf] = __builtin_amdgcn_mfma_f32_16x16x32_bf16(afh[mf], bfl[nf], acc[mf][nf], 0, 0, 0);
          acc[mf][nf] = __builtin_amdgcn_mfma_f32_16x16x32_bf16(afl[mf], bfh[nf], acc[mf][nf], 0, 0, 0);
        }
    }
    __syncthreads();
    if (more) {
      sstore();
      __syncthreads();
    }
  }

  // epilogue: C/D layout col=lane&15, row=(lane>>4)*4+reg (guide §3, m89/m91)
#pragma unroll
  for (int nf = 0; nf < 2; ++nf) {
    const int col = n0 + wn * 32 + nf * 16 + l15;
    float bb = 0.f;
    if (BIAS && col < N) bb = bias[col];
#pragma unroll
    for (int mf = 0; mf < 2; ++mf) {
      const int rbase = m0 + wm * 32 + mf * 16 + kg * 4;
#pragma unroll
      for (int i = 0; i < 4; ++i) {
        const int row = rbase + i;
        if (row >= M) continue;
        if (col < N) {
          float v = acc[mf][nf][i];
          if (BIAS) v += bb;
          if (RELU) v = fmaxf(v, 0.f);
          if (SPLIT) {
            us h = f2bf(v);
            Ch[(size_t)row * NPAD + col] = h;
            Cl[(size_t)row * NPAD + col] = f2bf(v - bf2f(h));
          } else {
            Cf[(size_t)row * N + col] = v;
          }
        } else if (SPLIT && col < NPAD) {  // zero the K-pad for next GEMM
          Ch[(size_t)row * NPAD + col] = 0;
          Cl[(size_t)row * NPAD + col] = 0;
        }
      }
    }
  }
}

// Fused gather-aggregate + self-loop + bias + relu.
// NPW nodes/wave; F/4 lanes per node, ONE float4 per edge per lane.
// 4-way edge unroll: 4 independent load->FMA chains in flight per wave.
// SPLIT: write bf16 hi/lo planes with row stride OST, zero-pad cols [F,OST).
template <int F, int OST, int NPW, bool SPLIT>
__global__ __launch_bounds__(256) void agg_gather_kernel(const int* __restrict__ rowptr,
                                                         const int* __restrict__ srcS,
                                                         const float* __restrict__ wS,
                                                         const float* __restrict__ t,
                                                         const float* __restrict__ dinv,
                                                         const float* __restrict__ bias,
                                                         float* __restrict__ out,
                                                         us* __restrict__ oh,
                                                         us* __restrict__ ol) {
  constexpr int LPN = F / 4;     // float4 lanes per node
  constexpr int LPNP = OST / 4;  // lanes incl. pad
  const int wv = threadIdx.x >> 6;
  const int lane = threadIdx.x & 63;
  const int sub = (NPW == 2) ? (lane >> 5) : 0;
  const int l = (NPW == 2) ? (lane & 31) : lane;
  const int node = blockIdx.x * (4 * NPW) + wv * NPW + sub;
  if (node >= NN) return;
  if (l >= LPN) {
    if (SPLIT && l < LPNP) {  // zero the K-pad for the next GEMM
      ushort4 z = make_ushort4(0, 0, 0, 0);
      *reinterpret_cast<ushort4*>(oh + (size_t)node * OST + l * 4) = z;
      *reinterpret_cast<ushort4*>(ol + (size_t)node * OST + l * 4) = z;
    }
    return;  // no barriers/shuffles below: safe exit
  }
  const int beg = rowptr[node], end = rowptr[node + 1];
  const size_t fo = (size_t)l * 4;
  float4 a0 = make_float4(0.f, 0.f, 0.f, 0.f);
  float4 a1 = a0, a2 = a0, a3 = a0;
  int j = beg;
  for (; j + 3 < end; j += 4) {  // 4 independent load->FMA chains
    const int s0 = srcS[j], s1 = srcS[j + 1], s2 = srcS[j + 2], s3 = srcS[j + 3];
    const float w0 = wS[j], w1 = wS[j + 1], w2 = wS[j + 2], w3 = wS[j + 3];
    const float4 v0 = *reinterpret_cast<const float4*>(t + (size_t)s0 * F + fo);
    const float4 v1 = *reinterpret_cast<const float4*>(t + (size_t)s1 * F + fo);
    const float4 v2 = *reinterpret_cast<const float4*>(t + (size_t)s2 * F + fo);
    const float4 v3 = *reinterpret_cast<const float4*>(t + (size_t)s3 * F + fo);
    a0.x = fmaf(v0.x, w0, a0.x); a0.y = fmaf(v0.y, w0, a0.y);
    a0.z = fmaf(v0.z, w0, a0.z); a0.w = fmaf(v0.w, w0, a0.w);
    a1.x = fmaf(v1.x, w1, a1.x); a1.y = fmaf(v1.y, w1, a1.y);
    a1.z = fmaf(v1.z, w1, a1.z); a1.w = fmaf(v1.w, w1, a1.w);
    a2.x = fmaf(v2.x, w2, a2.x); a2.y = fmaf(v2.y, w2, a2.y);
    a2.z = fmaf(v2.z, w2, a2.z); a2.w = fmaf(v2.w, w2, a2.w);
    a3.x = fmaf(v3.x, w3, a3.x); a3.y = fmaf(v3.y, w3, a3.y);
    a3.z = fmaf(v3.z, w3, a3.z); a3.w = fmaf(v3.w, w3, a3.w);
  }
  if (j + 1 < end) {  // 2-edge remainder
    const int s0 = srcS[j], s1 = srcS[j + 1];
    const float w0 = wS[j], w1 = wS[j + 1];
    const float4 v0 = *reinterpret_cast<const float4*>(t + (size_t)s0 * F + fo);
    const float4 v1 = *reinterpret_cast<const float4*>(t + (size_t)s1 * F + fo);
    a0.x = fmaf(v0.x, w0, a0.x); a0.y = fmaf(v0.y, w0, a0.y);
    a0.z = fmaf(v0.z, w0, a0.z); a0.w = fmaf(v0.w, w0, a0.w);
    a1.x = fmaf(v1.x, w1, a1.x); a1.y = fmaf(v1.y, w1, a1.y);
    a1.z = fmaf(v1.z, w1, a1.z); a1.w = fmaf(v1.w, w1, a1.w);
    j += 2;
  }
  if (j < end) {  // 1-edge remainder
    const int s0 = srcS[j];
    const float w0 = wS[j];
    const float4 v0 = *reinterpret_cast<const float4*>(t + (size_t)s0 * F + fo);
    a0.x = fmaf(v0.x, w0, a0.x); a0.y = fmaf(v0.y, w0, a0.y);
    a0.z = fmaf(v0.z, w0, a0.z); a0.w = fmaf(v0.w, w0, a0.w);
  }
  const float di = dinv[node];
  const float sw = di * di;
  const float4 tv = *reinterpret_cast<const float4*>(t + (size_t)node * F + fo);
  const float4 bb = *reinterpret_cast<const float4*>(bias + fo);
  float4 o;
  o.x = fmaxf(fmaf(tv.x, sw, (a0.x + a1.x) + (a2.x + a3.x)) + bb.x, 0.f);
  o.y = fmaxf(fmaf(tv.y, sw, (a0.y + a1.y) + (a2.y + a3.y)) + bb.y, 0.f);
  o.z = fmaxf(fmaf(tv.z, sw, (a0.z + a1.z) + (a2.z + a3.z)) + bb.z, 0.f);
  o.w = fmaxf(fmaf(tv.w, sw, (a0.w + a1.w) + (a2.w + a3.w)) + bb.w, 0.f);
  if (SPLIT) {
    ushort4 hv, lv;
    hv.x = f2bf(o.x); lv.x = f2bf(o.x - bf2f(hv.x));
    hv.y = f2bf(o.y); lv.y = f2bf(o.y - bf2f(hv.y));
    hv.z = f2bf(o.z); lv.z = f2bf(o.z - bf2f(hv.z));
    hv.w = f2bf(o.w); lv.w = f2bf(o.w - bf2f(hv.w));
    *reinterpret_cast<ushort4*>(oh + (size_t)node * OST + fo) = hv;
    *reinterpret_cast<ushort4*>(ol + (size_t)node * OST + fo) = lv;
  } else {
    *reinterpret_cast<float4*>(out + (size_t)node * F + fo) = o;
  }
}

extern "C" void kernel_launch(void* const* d_in, const int* in_sizes, int n_in,
                              void* d_out, int out_size, void* d_ws, size_t ws_size,
                              hipStream_t stream) {
  const float* x = (const float*)d_in[0];
  const int* ei = (const int*)d_in[1];  // int32 per harness conversion
  const float* ea = (const float*)d_in[2];
  const float* fcW = (const float*)d_in[3];
  const float* fcb = (const float*)d_in[4];
  const float* W1 = (const float*)d_in[5];
  const float* b1 = (const float*)d_in[6];
  const float* W2 = (const float*)d_in[7];
  const float* b2 = (const float*)d_in[8];
  const int* srcIdx = ei;       // edge_index[0]
  const int* dstIdx = ei + NE;  // edge_index[1]

  char* ws = (char*)d_ws;
  constexpr size_t KB_ = 1u << 10;
  float* dinv = (float*)(ws);                    // 80000 B (doubles as deg)
  int* cnt = (int*)(ws + 80000);                 // 80000 B (count -> cursor)
  int* rowptr = (int*)(ws + 160000);             // 80004 B
  int* bsum = (int*)(ws + 244 * KB_);            // 320 B
  int* srcS = (int*)(ws + 256 * KB_);            // 1.28 MB
  float* wS = (float*)(ws + 1536 * KB_);         // 1.28 MB
  us* fcWTh = (us*)(ws + 2880 * KB_);            // 204800 B
  us* fcWTl = (us*)(ws + 3088 * KB_);
  us* W1Th = (us*)(ws + 3296 * KB_);             // 200x448x2 = 179200 B
  us* W1Tl = (us*)(ws + 3472 * KB_);
  us* W2Th = (us*)(ws + 3648 * KB_);             // 128x256x2 = 65536 B
  us* W2Tl = (us*)(ws + 3712 * KB_);             // ends exactly at 3776 KB
  us* xh = (us*)(ws + 3776 * KB_);               // 10.24 MB
  us* xl = (us*)(ws + 13784 * KB_);              // ends ~23.8 MB
  us* h1h = (us*)(ws + 23800 * KB_);             // 20000x448x2 = 17.92 MB
  us* h1l = (us*)(ws + 41350 * KB_);             // ends ~57.5 MB (peak)
  float* t1 = (float*)(ws + 3776 * KB_);         // 16 MB (x dead); also t2
  us* h2h = (us*)(ws + 23800 * KB_);             // 10.24 MB (h1 dead)
  us* h2l = (us*)(ws + 33800 * KB_);
  float* t2 = (float*)(ws + 3776 * KB_);         // 10.24 MB (t1 dead)

  // --- front-end: zero; {atomics + x-split + w-transpose}; scan; scatter ---
  zero_kernel<<<(40000 / 4 + 255) / 256, 256, 0, stream>>>((float4*)ws, 40000 / 4);
  front_kernel<<<2560, 256, 0, stream>>>(dstIdx, ea, dinv, cnt, x, xh, xl,
                                         fcW, W1, W2, fcWTh, fcWTl,
                                         W1Th, W1Tl, W2Th, W2Tl);
  blocksum_dinv_kernel<<<SBLK, 256, 0, stream>>>(cnt, bsum, dinv);
  rowptr_kernel<<<SBLK, 256, 0, stream>>>(bsum, cnt, rowptr);
  scatter_kernel<<<(NE + 255) / 256, 256, 0, stream>>>(srcIdx, dstIdx, ea, dinv, cnt, srcS, wS);

  const int MBLK = (NN + 63) / 64;  // 313 row blocks

  // --- h1 = relu(x @ fcW + fcb), bf16 hi/lo planes [NN][448] ---
  gemm64_kernel<IN_FT, true, true, true><<<7 * MBLK, 256, 0, stream>>>(
      xh, xl, fcWTh, fcWTl, fcb, nullptr, h1h, h1l, NN, HID1, K1P, 7);

  // --- layer 1: t1 = h1 @ W1 (fp32); h2 = relu(agg(t1)+..) planes [NN][256] ---
  gemm64_kernel<K1P, false, false, false><<<4 * MBLK, 256, 0, stream>>>(
      h1h, h1l, W1Th, W1Tl, nullptr, t1, nullptr, nullptr, NN, HID2, HID2, 4);
  agg_gather_kernel<HID2, K2P, 1, true><<<(NN + 3) / 4, 256, 0, stream>>>(
      rowptr, srcS, wS, t1, dinv, b1, nullptr, h2h, h2l);

  // --- layer 2: t2 = h2 @ W2 (fp32); out = relu(agg(t2)+..) fp32 ---
  gemm64_kernel<K2P, false, false, false><<<2 * MBLK, 256, 0, stream>>>(
      h2h, h2l, W2Th, W2Tl, nullptr, t2, nullptr, nullptr, NN, OUT_FT, OUT_FT, 2);
  agg_gather_kernel<OUT_FT, OUT_FT, 2, false><<<(NN + 7) / 8, 256, 0, stream>>>(
      rowptr, srcS, wS, t2, dinv, b2, (float*)d_out, nullptr, nullptr);
}